// Round 1
// 441.137 us; speedup vs baseline: 1.1138x; 1.1138x over previous
//
#include <hip/hip_runtime.h>
#include <stdint.h>

typedef unsigned int u32;
typedef unsigned long long u64;

constexpr int L   = 4;
constexpr int S   = 4;
constexpr int NM  = 16;
constexpr int HID = 32;
constexpr int BLK = 256;
constexpr int NFRAG = 7;                       // A-frags per (l,s): L1:1, L2:2, L3:2, L4:2
constexpr int WF_ENTRIES = L * S * NFRAG * 64; // 7168 uint4 entries
constexpr int WS_PERM_INT = (256 + WF_ENTRIES * 16) / 4;  // perm after hdr+wfrag

typedef short  s16x8  __attribute__((ext_vector_type(8)));
typedef float  f32x16 __attribute__((ext_vector_type(16)));

// ws: [0,64B) hdr ints: [0..3] counts, [4..7] cursors, [8..12] basePad,
//     [13] fp32 flag, [14] int64 flag. wfrag uint4 at byte 256. perm at int WS_PERM_INT.

// Merged init + format detect (one wave). Every hdr slot 0..15 written exactly once.
__global__ void k_detect(const u32* __restrict__ rfw, const u32* __restrict__ spw,
                         int* __restrict__ hdr) {
    int t = threadIdx.x;  // one wave
    if (t < 16 && t != 13 && t != 14) hdr[t] = 0;
    u32 w  = rfw[t];
    u32 lo = w & 0xffffu;
    u32 e  = (lo >> 7) & 0xffu;
    int plausible = (lo == 0u || (e >= 90u && e <= 141u)) ? 1 : 0;
    u64 pm = __ballot(plausible);
    u64 om = __ballot(spw[2 * t + 1] != 0u);
    if (t == 0) {
        hdr[13] = (__popcll(pm) < 48) ? 1 : 0;  // floats are fp32
        hdr[14] = (om == 0ull) ? 1 : 0;         // species is int64
    }
}

__device__ __forceinline__ int load_species(const int* sp, int i64, int n) {
    return i64 ? sp[2 * n] : sp[n];
}

__global__ void k1_hist(const int* __restrict__ sp, int* __restrict__ hdr, int N) {
    __shared__ int cnt[S];
    int t = threadIdx.x;
    int n = blockIdx.x * BLK + t;
    if (t < S) cnt[t] = 0;
    int i64 = hdr[14];
    __syncthreads();
    if (n < N) atomicAdd(&cnt[load_species(sp, i64, n)], 1);
    __syncthreads();
    if (t < S) atomicAdd(&hdr[t], cnt[t]);
}

__global__ void k2_scan(int* __restrict__ hdr, int* __restrict__ perm) {
    __shared__ int bp[S + 1];
    __shared__ int cs[S];
    int t = threadIdx.x;
    if (t == 0) {
        int acc = 0;
        for (int s = 0; s < S; s++) {
            bp[s] = acc;
            cs[s] = hdr[s];
            acc += (cs[s] + BLK - 1) & ~(BLK - 1);
        }
        bp[S] = acc;
        for (int s = 0; s < S; s++) hdr[4 + s] = bp[s];
        for (int j = 0; j <= S; j++) hdr[8 + j] = bp[j];
    }
    __syncthreads();
    for (int s = 0; s < S; s++) {
        for (int i = bp[s] + cs[s] + t; i < bp[s + 1]; i += blockDim.x) perm[i] = -1;
    }
}

__global__ void k3_scatter(const int* __restrict__ sp, int* __restrict__ hdr,
                           int* __restrict__ perm, int N) {
    __shared__ int cnt[S];
    __shared__ int base[S];
    int t = threadIdx.x;
    int n = blockIdx.x * BLK + t;
    if (t < S) cnt[t] = 0;
    int i64 = hdr[14];
    __syncthreads();
    int s = 0, r = 0;
    bool valid = (n < N);
    if (valid) {
        s = load_species(sp, i64, n);
        r = atomicAdd(&cnt[s], 1);
    }
    __syncthreads();
    if (t < S) base[t] = atomicAdd(&hdr[4 + t], cnt[t]);
    __syncthreads();
    if (valid) perm[base[s] + r] = n;
}

// Pre-swizzle weights into 32x32x16 A-fragment order (transposed: A[m=out][k=in]).
// Entry e = ((l*S+s)*NFRAG + f)*64 + lane. Lane holds k = 8*(lane>>5)+j, m = lane&31.
__global__ void k_wprep(const void* __restrict__ W1, const void* __restrict__ W2,
                        const void* __restrict__ W3, const void* __restrict__ W4,
                        const int* __restrict__ hdr, uint4* __restrict__ wf) {
    int e = blockIdx.x * BLK + threadIdx.x;
    if (e >= WF_ENTRIES) return;
    int lam = e & 63;
    int f   = (e >> 6) % NFRAG;
    int ls  = e / (64 * NFRAG);
    int m = lam & 31, h = lam >> 5;
    int isf32 = hdr[13];
    unsigned short vals[8];
#pragma unroll
    for (int j = 0; j < 8; j++) {
        int k = 8 * h + j;
        const void* base; size_t off; bool zero = false;
        if (f == 0)      { base = W1; off = (size_t)ls * 512  + (size_t)k * 32 + m; }
        else if (f <= 2) { base = W2; off = (size_t)ls * 1024 + (size_t)(k + 16 * (f - 1)) * 32 + m; }
        else if (f <= 4) { base = W3; off = (size_t)ls * 1024 + (size_t)(k + 16 * (f - 3)) * 32 + m; }
        else             { zero = (m >= NM); base = W4;
                           off = (size_t)ls * 512 + (size_t)(k + 16 * (f - 5)) * NM + (m & 15); }
        unsigned short v;
        if (zero) v = 0;
        else if (isf32) {
            u32 u = __float_as_uint(((const float*)base)[off]);
            u32 r = ((u >> 16) & 1u) + 0x7fffu;
            v = (unsigned short)((u + r) >> 16);
        } else v = ((const unsigned short*)base)[off];
        vals[j] = v;
    }
    uint4 q;
    q.x = vals[0] | ((u32)vals[1] << 16);
    q.y = vals[2] | ((u32)vals[3] << 16);
    q.z = vals[4] | ((u32)vals[5] << 16);
    q.w = vals[6] | ((u32)vals[7] << 16);
    wf[e] = q;
}

__device__ __forceinline__ u32 pack_bf16_hu(float a, float b) {
    u32 ua = __float_as_uint(a) + 0x8000u;   // round half-up
    u32 ub = __float_as_uint(b) + 0x8000u;
    return (ua >> 16) | (ub & 0xffff0000u);
}

__device__ __forceinline__ float silu(float v) {
    float e = __expf(-v);
    return v * __builtin_amdgcn_rcpf(1.0f + e);
}

// D (C/D layout) -> next-layer B frags (Ba: k=0..15, Bb: k=16..31), with SiLU.
__device__ __forceinline__ void d_to_b(const f32x16& d, int h, s16x8& Ba, s16x8& Bb) {
    u32 P[8];
#pragma unroll
    for (int i = 0; i < 8; i++)
        P[i] = pack_bf16_hu(silu(d[2 * i]), silu(d[2 * i + 1]));
    u32 E[8];
#pragma unroll
    for (int i = 0; i < 8; i++) E[i] = (u32)__shfl_xor((int)P[i], 32, 64);
    u32 q[8];
#pragma unroll
    for (int b = 0; b < 2; b++) {
        int idx = 2 * h + 4 * b;
        q[4 * b + 0] = h ? E[idx]     : P[idx];
        q[4 * b + 1] = h ? E[idx + 1] : P[idx + 1];
        q[4 * b + 2] = h ? P[idx]     : E[idx];
        q[4 * b + 3] = h ? P[idx + 1] : E[idx + 1];
    }
    Ba = __builtin_bit_cast(s16x8, make_uint4(q[0], q[1], q[2], q[3]));
    Bb = __builtin_bit_cast(s16x8, make_uint4(q[4], q[5], q[6], q[7]));
}

__global__ __launch_bounds__(BLK, 4) void k4_mlp(
    const void* __restrict__ rf, const int* __restrict__ hdr,
    const int* __restrict__ perm, const uint4* __restrict__ wf,
    void* __restrict__ outp)
{
    __shared__ uint4 lw[L * NFRAG * 64];   // 28 KB, fragment order
    __shared__ float sc[4][32 * 17];       // 8.5 KB: per-wave output transpose scratch
    __shared__ int   sn[4][2][32];         // 1 KB: per-wave pair indices

    int p0 = blockIdx.x * BLK;
    int b1 = hdr[9], b2 = hdr[10], b3 = hdr[11], b4 = hdr[12];
    int isf32 = hdr[13];
    if (p0 >= b4) return;
    int s = (p0 >= b3) ? 3 : ((p0 >= b2) ? 2 : ((p0 >= b1) ? 1 : 0));
    s = __builtin_amdgcn_readfirstlane(s);

#pragma unroll
    for (int c = 0; c < 7; c++) {
        int idx = threadIdx.x + c * BLK;   // < 1792
        int l = idx / (NFRAG * 64);
        int r = idx - l * (NFRAG * 64);
        lw[idx] = wf[(size_t)((l * S + s) * NFRAG) * 64 + r];
    }

    int wv   = threadIdx.x >> 6;
    int lane = threadIdx.x & 63;
    int col  = lane & 31;
    int h    = lane >> 5;

    int n_t[2];
#pragma unroll
    for (int t = 0; t < 2; t++) {
        n_t[t] = perm[p0 + wv * 64 + t * 32 + col];
        sn[wv][t][col] = n_t[t];
    }
    __syncthreads();

    if (isf32) {
        // ---------- fp32 path: depth-1 prefetch + LDS-transposed coalesced stores ----
        const char* xb = (const char*)rf;
        int nn0 = n_t[0] < 0 ? 0 : n_t[0];
        int nn1 = n_t[1] < 0 ? 0 : n_t[1];
        const uint4* r0 = (const uint4*)(xb + (size_t)nn0 * 256 + h * 32);
        const uint4* r1 = (const uint4*)(xb + (size_t)nn1 * 256 + h * 32);

        uint4 raw[4][2][2];                // [l][t][16B half]; constant-indexed after unroll
        raw[0][0][0] = r0[0]; raw[0][0][1] = r0[1];
        raw[0][1][0] = r1[0]; raw[0][1][1] = r1[1];

        int jr = lane >> 2;                // 0..15: output row group within wave
        int cc = lane & 3;                 // 16B chunk within a 64B line

#pragma unroll
        for (int l = 0; l < L; l++) {
            if (l < 3) {                   // prefetch next l (both t) — hides HBM latency
                raw[l + 1][0][0] = r0[(l + 1) * 4];
                raw[l + 1][0][1] = r0[(l + 1) * 4 + 1];
                raw[l + 1][1][0] = r1[(l + 1) * 4];
                raw[l + 1][1][1] = r1[(l + 1) * 4 + 1];
            }
            s16x8 fr[NFRAG];
#pragma unroll
            for (int f = 0; f < NFRAG; f++)
                fr[f] = __builtin_bit_cast(s16x8, lw[(l * NFRAG + f) * 64 + lane]);

#pragma unroll
            for (int t = 0; t < 2; t++) {
                uint4 q0 = raw[l][t][0], q1 = raw[l][t][1];
                u32 w0 = pack_bf16_hu(__uint_as_float(q0.x), __uint_as_float(q0.y));
                u32 w1 = pack_bf16_hu(__uint_as_float(q0.z), __uint_as_float(q0.w));
                u32 w2 = pack_bf16_hu(__uint_as_float(q1.x), __uint_as_float(q1.y));
                u32 w3 = pack_bf16_hu(__uint_as_float(q1.z), __uint_as_float(q1.w));
                s16x8 B1 = __builtin_bit_cast(s16x8, make_uint4(w0, w1, w2, w3));

                f32x16 z = {0.0f};
                f32x16 d1 = __builtin_amdgcn_mfma_f32_32x32x16_bf16(fr[0], B1, z, 0, 0, 0);

                s16x8 Ba, Bb;
                d_to_b(d1, h, Ba, Bb);
                f32x16 d2 = __builtin_amdgcn_mfma_f32_32x32x16_bf16(fr[1], Ba, z, 0, 0, 0);
                d2 = __builtin_amdgcn_mfma_f32_32x32x16_bf16(fr[2], Bb, d2, 0, 0, 0);

                d_to_b(d2, h, Ba, Bb);
                f32x16 d3 = __builtin_amdgcn_mfma_f32_32x32x16_bf16(fr[3], Ba, z, 0, 0, 0);
                d3 = __builtin_amdgcn_mfma_f32_32x32x16_bf16(fr[4], Bb, d3, 0, 0, 0);

                d_to_b(d3, h, Ba, Bb);
                f32x16 d4 = __builtin_amdgcn_mfma_f32_32x32x16_bf16(fr[5], Ba, z, 0, 0, 0);
                d4 = __builtin_amdgcn_mfma_f32_32x32x16_bf16(fr[6], Bb, d4, 0, 0, 0);

                // stage own 8 features in LDS (no shfl): lane (col,h) owns
                // features 4h..4h+3 (d4[0..3]) and 8+4h..11+4h (d4[4..7])
                float* scw = &sc[wv][col * 17 + 4 * h];
                scw[0] = d4[0]; scw[1] = d4[1]; scw[2]  = d4[2]; scw[3]  = d4[3];
                scw[8] = d4[4]; scw[9] = d4[5]; scw[10] = d4[6]; scw[11] = d4[7];

                asm volatile("s_waitcnt lgkmcnt(0)" ::: "memory");
                __builtin_amdgcn_sched_barrier(0);

                // coalesced store: 4 consecutive lanes cover one full 64B line
#pragma unroll
                for (int p = 0; p < 2; p++) {
                    int r = 16 * p + jr;
                    int n = sn[wv][t][r];
                    const float* srd = &sc[wv][r * 17 + 4 * cc];
                    float4 v = { srd[0], srd[1], srd[2], srd[3] };
                    if (n >= 0)
                        *(float4*)((char*)outp + (size_t)n * 256 + l * 64 + cc * 16) = v;
                }
                asm volatile("s_waitcnt lgkmcnt(0)" ::: "memory");
                __builtin_amdgcn_sched_barrier(0);
            }
        }
    } else {
        // ---------- bf16 path (unchanged semantics) ----------
        for (int l = 0; l < L; l++) {
            s16x8 fr[NFRAG];
#pragma unroll
            for (int f = 0; f < NFRAG; f++)
                fr[f] = __builtin_bit_cast(s16x8, lw[(l * NFRAG + f) * 64 + lane]);

#pragma unroll
            for (int t = 0; t < 2; t++) {
                int n = n_t[t];
                int nn = n < 0 ? 0 : n;

                const char* xb = (const char*)rf;
                s16x8 B1 = __builtin_bit_cast(s16x8,
                     *(const uint4*)(xb + (size_t)nn * 128 + l * 32 + h * 16));

                f32x16 z = {0.0f};
                f32x16 d1 = __builtin_amdgcn_mfma_f32_32x32x16_bf16(fr[0], B1, z, 0, 0, 0);

                s16x8 Ba, Bb;
                d_to_b(d1, h, Ba, Bb);
                f32x16 d2 = __builtin_amdgcn_mfma_f32_32x32x16_bf16(fr[1], Ba, z, 0, 0, 0);
                d2 = __builtin_amdgcn_mfma_f32_32x32x16_bf16(fr[2], Bb, d2, 0, 0, 0);

                d_to_b(d2, h, Ba, Bb);
                f32x16 d3 = __builtin_amdgcn_mfma_f32_32x32x16_bf16(fr[3], Ba, z, 0, 0, 0);
                d3 = __builtin_amdgcn_mfma_f32_32x32x16_bf16(fr[4], Bb, d3, 0, 0, 0);

                d_to_b(d3, h, Ba, Bb);
                f32x16 d4 = __builtin_amdgcn_mfma_f32_32x32x16_bf16(fr[5], Ba, z, 0, 0, 0);
                d4 = __builtin_amdgcn_mfma_f32_32x32x16_bf16(fr[6], Bb, d4, 0, 0, 0);

                u32 P[4];
#pragma unroll
                for (int i = 0; i < 4; i++) P[i] = pack_bf16_hu(d4[2 * i], d4[2 * i + 1]);
                u32 E[4];
#pragma unroll
                for (int i = 0; i < 4; i++) E[i] = (u32)__shfl_xor((int)P[i], 32, 64);
                if (n >= 0) {
                    uint4 v = h ? make_uint4(E[2], E[3], P[2], P[3])
                                : make_uint4(P[0], P[1], E[0], E[1]);
                    char* ob = (char*)outp;
                    *(uint4*)(ob + (size_t)n * 128 + l * 32 + h * 16) = v;
                }
            }
        }
    }
}

extern "C" void kernel_launch(void* const* d_in, const int* in_sizes, int n_in,
                              void* d_out, int out_size, void* d_ws, size_t ws_size,
                              hipStream_t stream) {
    const void* rf     = d_in[0];
    const int* species = (const int*)d_in[1];
    const void* W1     = d_in[2];
    const void* W2     = d_in[3];
    const void* W3     = d_in[4];
    const void* W4     = d_in[5];

    int N = in_sizes[1];
    int* hdr   = (int*)d_ws;
    uint4* wf  = (uint4*)((char*)d_ws + 256);
    int* perm  = (int*)d_ws + WS_PERM_INT;

    int nb    = (N + BLK - 1) / BLK;
    int nwp   = (WF_ENTRIES + BLK - 1) / BLK;
    int grid4 = (N + S * (BLK - 1) + BLK - 1) / BLK;

    k_detect <<<dim3(1),    dim3(64),  0, stream>>>((const u32*)rf, (const u32*)species, hdr);
    k_wprep  <<<dim3(nwp),  dim3(BLK), 0, stream>>>(W1, W2, W3, W4, hdr, wf);
    k1_hist  <<<dim3(nb),   dim3(BLK), 0, stream>>>(species, hdr, N);
    k2_scan  <<<dim3(1),    dim3(BLK), 0, stream>>>(hdr, perm);
    k3_scatter<<<dim3(nb),  dim3(BLK), 0, stream>>>(species, hdr, perm, N);
    k4_mlp   <<<dim3(grid4),dim3(BLK), 0, stream>>>(rf, hdr, perm, wf, d_out);
}

// Round 2
// 390.519 us; speedup vs baseline: 1.2582x; 1.1296x over previous
//
#include <hip/hip_runtime.h>
#include <stdint.h>

typedef unsigned int u32;
typedef unsigned long long u64;

constexpr int L   = 4;
constexpr int S   = 4;
constexpr int NM  = 16;
constexpr int HID = 32;
constexpr int BLK = 256;
constexpr int NFRAG = 7;                       // A-frags per (l,s): L1:1, L2:2, L3:2, L4:2
constexpr int WF_ENTRIES = L * S * NFRAG * 64; // 7168 uint4 entries
constexpr int WS_PERM_INT = (256 + WF_ENTRIES * 16) / 4;  // perm after hdr+wfrag

typedef short  s16x8  __attribute__((ext_vector_type(8)));
typedef float  f32x16 __attribute__((ext_vector_type(16)));

// ws: [0,64B) hdr ints: [0..3] counts, [4..7] cursors, [8..12] basePad,
//     [13] fp32 flag, [14] int64 flag. wfrag uint4 at byte 256. perm at int WS_PERM_INT.

// Merged init + format detect (one wave). Every hdr slot 0..15 written exactly once.
__global__ void k_detect(const u32* __restrict__ rfw, const u32* __restrict__ spw,
                         int* __restrict__ hdr) {
    int t = threadIdx.x;  // one wave
    if (t < 16 && t != 13 && t != 14) hdr[t] = 0;
    u32 w  = rfw[t];
    u32 lo = w & 0xffffu;
    u32 e  = (lo >> 7) & 0xffu;
    int plausible = (lo == 0u || (e >= 90u && e <= 141u)) ? 1 : 0;
    u64 pm = __ballot(plausible);
    u64 om = __ballot(spw[2 * t + 1] != 0u);
    if (t == 0) {
        hdr[13] = (__popcll(pm) < 48) ? 1 : 0;  // floats are fp32
        hdr[14] = (om == 0ull) ? 1 : 0;         // species is int64
    }
}

__device__ __forceinline__ int load_species(const int* sp, int i64, int n) {
    return i64 ? sp[2 * n] : sp[n];
}

__global__ void k1_hist(const int* __restrict__ sp, int* __restrict__ hdr, int N) {
    __shared__ int cnt[S];
    int t = threadIdx.x;
    int n = blockIdx.x * BLK + t;
    if (t < S) cnt[t] = 0;
    int i64 = hdr[14];
    __syncthreads();
    if (n < N) atomicAdd(&cnt[load_species(sp, i64, n)], 1);
    __syncthreads();
    if (t < S) atomicAdd(&hdr[t], cnt[t]);
}

__global__ void k2_scan(int* __restrict__ hdr, int* __restrict__ perm) {
    __shared__ int bp[S + 1];
    __shared__ int cs[S];
    int t = threadIdx.x;
    if (t == 0) {
        int acc = 0;
        for (int s = 0; s < S; s++) {
            bp[s] = acc;
            cs[s] = hdr[s];
            acc += (cs[s] + BLK - 1) & ~(BLK - 1);
        }
        bp[S] = acc;
        for (int s = 0; s < S; s++) hdr[4 + s] = bp[s];
        for (int j = 0; j <= S; j++) hdr[8 + j] = bp[j];
    }
    __syncthreads();
    for (int s = 0; s < S; s++) {
        for (int i = bp[s] + cs[s] + t; i < bp[s + 1]; i += blockDim.x) perm[i] = -1;
    }
}

__global__ void k3_scatter(const int* __restrict__ sp, int* __restrict__ hdr,
                           int* __restrict__ perm, int N) {
    __shared__ int cnt[S];
    __shared__ int base[S];
    int t = threadIdx.x;
    int n = blockIdx.x * BLK + t;
    if (t < S) cnt[t] = 0;
    int i64 = hdr[14];
    __syncthreads();
    int s = 0, r = 0;
    bool valid = (n < N);
    if (valid) {
        s = load_species(sp, i64, n);
        r = atomicAdd(&cnt[s], 1);
    }
    __syncthreads();
    if (t < S) base[t] = atomicAdd(&hdr[4 + t], cnt[t]);
    __syncthreads();
    if (valid) perm[base[s] + r] = n;
}

// Pre-swizzle weights into 32x32x16 A-fragment order (transposed: A[m=out][k=in]).
// Entry e = ((l*S+s)*NFRAG + f)*64 + lane. Lane holds k = 8*(lane>>5)+j, m = lane&31.
__global__ void k_wprep(const void* __restrict__ W1, const void* __restrict__ W2,
                        const void* __restrict__ W3, const void* __restrict__ W4,
                        const int* __restrict__ hdr, uint4* __restrict__ wf) {
    int e = blockIdx.x * BLK + threadIdx.x;
    if (e >= WF_ENTRIES) return;
    int lam = e & 63;
    int f   = (e >> 6) % NFRAG;
    int ls  = e / (64 * NFRAG);
    int m = lam & 31, h = lam >> 5;
    int isf32 = hdr[13];
    unsigned short vals[8];
#pragma unroll
    for (int j = 0; j < 8; j++) {
        int k = 8 * h + j;
        const void* base; size_t off; bool zero = false;
        if (f == 0)      { base = W1; off = (size_t)ls * 512  + (size_t)k * 32 + m; }
        else if (f <= 2) { base = W2; off = (size_t)ls * 1024 + (size_t)(k + 16 * (f - 1)) * 32 + m; }
        else if (f <= 4) { base = W3; off = (size_t)ls * 1024 + (size_t)(k + 16 * (f - 3)) * 32 + m; }
        else             { zero = (m >= NM); base = W4;
                           off = (size_t)ls * 512 + (size_t)(k + 16 * (f - 5)) * NM + (m & 15); }
        unsigned short v;
        if (zero) v = 0;
        else if (isf32) {
            u32 u = __float_as_uint(((const float*)base)[off]);
            u32 r = ((u >> 16) & 1u) + 0x7fffu;
            v = (unsigned short)((u + r) >> 16);
        } else v = ((const unsigned short*)base)[off];
        vals[j] = v;
    }
    uint4 q;
    q.x = vals[0] | ((u32)vals[1] << 16);
    q.y = vals[2] | ((u32)vals[3] << 16);
    q.z = vals[4] | ((u32)vals[5] << 16);
    q.w = vals[6] | ((u32)vals[7] << 16);
    wf[e] = q;
}

__device__ __forceinline__ u32 pack_bf16_hu(float a, float b) {
    u32 ua = __float_as_uint(a) + 0x8000u;   // round half-up
    u32 ub = __float_as_uint(b) + 0x8000u;
    return (ua >> 16) | (ub & 0xffff0000u);
}

__device__ __forceinline__ float silu(float v) {
    float e = __expf(-v);
    return v * __builtin_amdgcn_rcpf(1.0f + e);
}

// D (C/D layout) -> next-layer B frags (Ba: k=0..15, Bb: k=16..31), with SiLU.
__device__ __forceinline__ void d_to_b(const f32x16& d, int h, s16x8& Ba, s16x8& Bb) {
    u32 P[8];
#pragma unroll
    for (int i = 0; i < 8; i++)
        P[i] = pack_bf16_hu(silu(d[2 * i]), silu(d[2 * i + 1]));
    u32 E[8];
#pragma unroll
    for (int i = 0; i < 8; i++) E[i] = (u32)__shfl_xor((int)P[i], 32, 64);
    u32 q[8];
#pragma unroll
    for (int b = 0; b < 2; b++) {
        int idx = 2 * h + 4 * b;
        q[4 * b + 0] = h ? E[idx]     : P[idx];
        q[4 * b + 1] = h ? E[idx + 1] : P[idx + 1];
        q[4 * b + 2] = h ? P[idx]     : E[idx];
        q[4 * b + 3] = h ? P[idx + 1] : E[idx + 1];
    }
    Ba = __builtin_bit_cast(s16x8, make_uint4(q[0], q[1], q[2], q[3]));
    Bb = __builtin_bit_cast(s16x8, make_uint4(q[4], q[5], q[6], q[7]));
}

// Per-wave output scratch stride (words per 64-float half-row-pair entry).
// 32 data words + 4 pad -> b128-aligned, conflict-free for our write/read patterns.
constexpr int SCW = 36;

__global__ __launch_bounds__(BLK, 4) void k4_mlp(
    const void* __restrict__ rf, const int* __restrict__ hdr,
    const int* __restrict__ perm, const uint4* __restrict__ wf,
    void* __restrict__ outp)
{
    __shared__ uint4 lw[L * NFRAG * 64];     // 28 KB, fragment order
    __shared__ float sc[4][32 * SCW];        // 18 KB: per-wave half-row transpose scratch
    __shared__ int   sn[4][2][32];           // 1 KB: per-wave pair indices

    int p0 = blockIdx.x * BLK;
    int b1 = hdr[9], b2 = hdr[10], b3 = hdr[11], b4 = hdr[12];
    int isf32 = hdr[13];
    if (p0 >= b4) return;
    int s = (p0 >= b3) ? 3 : ((p0 >= b2) ? 2 : ((p0 >= b1) ? 1 : 0));
    s = __builtin_amdgcn_readfirstlane(s);

#pragma unroll
    for (int c = 0; c < 7; c++) {
        int idx = threadIdx.x + c * BLK;   // < 1792
        int l = idx / (NFRAG * 64);
        int r = idx - l * (NFRAG * 64);
        lw[idx] = wf[(size_t)((l * S + s) * NFRAG) * 64 + r];
    }

    int wv   = threadIdx.x >> 6;
    int lane = threadIdx.x & 63;
    int col  = lane & 31;
    int h    = lane >> 5;

    int n_t[2];
#pragma unroll
    for (int t = 0; t < 2; t++) {
        n_t[t] = perm[p0 + wv * 64 + t * 32 + col];
        sn[wv][t][col] = n_t[t];
    }
    __syncthreads();

    if (isf32) {
        // ---------- fp32 path: lp-outer/t-middle/l-inner; full-128B-line stores ----
        const char* xb = (const char*)rf;
        int nn0 = n_t[0] < 0 ? 0 : n_t[0];
        int nn1 = n_t[1] < 0 ? 0 : n_t[1];
        const uint4* rp0 = (const uint4*)(xb + (size_t)nn0 * 256 + h * 32);
        const uint4* rp1 = (const uint4*)(xb + (size_t)nn1 * 256 + h * 32);

        int rg = lane >> 3;                // 0..7: row group for stores
        int cc = lane & 7;                 // 0..7: 16B chunk within a 128B half-row
        float* scb = &sc[wv][0];

        // double-buffered input rows: rawb[buf][ li*2 + half ]
        uint4 rawb[2][4];
        rawb[0][0] = rp0[0]; rawb[0][1] = rp0[1];   // lp=0,t=0: l=0
        rawb[0][2] = rp0[4]; rawb[0][3] = rp0[5];   //           l=1

#pragma unroll
        for (int j = 0; j < 4; j++) {               // j = lp*2 + t
            int lp = j >> 1, t = j & 1;
            if (j < 3) {                            // prefetch next (lp,t)
                int jn = j + 1;
                int lpn = jn >> 1, tn = jn & 1;
                const uint4* pl = tn ? rp1 : rp0;
                rawb[jn & 1][0] = pl[lpn * 8 + 0];
                rawb[jn & 1][1] = pl[lpn * 8 + 1];
                rawb[jn & 1][2] = pl[lpn * 8 + 4];
                rawb[jn & 1][3] = pl[lpn * 8 + 5];
            }
#pragma unroll
            for (int li = 0; li < 2; li++) {
                int l = 2 * lp + li;
                s16x8 fr[NFRAG];
#pragma unroll
                for (int f = 0; f < NFRAG; f++)
                    fr[f] = __builtin_bit_cast(s16x8, lw[(l * NFRAG + f) * 64 + lane]);

                uint4 q0 = rawb[j & 1][li * 2 + 0];
                uint4 q1 = rawb[j & 1][li * 2 + 1];
                u32 w0 = pack_bf16_hu(__uint_as_float(q0.x), __uint_as_float(q0.y));
                u32 w1 = pack_bf16_hu(__uint_as_float(q0.z), __uint_as_float(q0.w));
                u32 w2 = pack_bf16_hu(__uint_as_float(q1.x), __uint_as_float(q1.y));
                u32 w3 = pack_bf16_hu(__uint_as_float(q1.z), __uint_as_float(q1.w));
                s16x8 B1 = __builtin_bit_cast(s16x8, make_uint4(w0, w1, w2, w3));

                f32x16 z = {0.0f};
                f32x16 d1 = __builtin_amdgcn_mfma_f32_32x32x16_bf16(fr[0], B1, z, 0, 0, 0);

                s16x8 Ba, Bb;
                d_to_b(d1, h, Ba, Bb);
                f32x16 d2 = __builtin_amdgcn_mfma_f32_32x32x16_bf16(fr[1], Ba, z, 0, 0, 0);
                d2 = __builtin_amdgcn_mfma_f32_32x32x16_bf16(fr[2], Bb, d2, 0, 0, 0);

                d_to_b(d2, h, Ba, Bb);
                f32x16 d3 = __builtin_amdgcn_mfma_f32_32x32x16_bf16(fr[3], Ba, z, 0, 0, 0);
                d3 = __builtin_amdgcn_mfma_f32_32x32x16_bf16(fr[4], Bb, d3, 0, 0, 0);

                d_to_b(d3, h, Ba, Bb);
                f32x16 d4 = __builtin_amdgcn_mfma_f32_32x32x16_bf16(fr[5], Ba, z, 0, 0, 0);
                d4 = __builtin_amdgcn_mfma_f32_32x32x16_bf16(fr[6], Bb, d4, 0, 0, 0);

                // stash own features: lane (col,h) owns feats 4h..4h+3 and 8+4h..11+4h
                // of pair col; scratch word = li*16 + feat
                float* scw = scb + col * SCW + li * 16 + 4 * h;
                *(float4*)scw       = make_float4(d4[0], d4[1], d4[2], d4[3]);
                *(float4*)(scw + 8) = make_float4(d4[4], d4[5], d4[6], d4[7]);
            }
            asm volatile("s_waitcnt lgkmcnt(0)" ::: "memory");
            __builtin_amdgcn_sched_barrier(0);

            // 4 store instrs; each: 8 lanes cover one FULL 128B-aligned half-row
#pragma unroll
            for (int i = 0; i < 4; i++) {
                int r = 8 * i + rg;
                int n = sn[wv][t][r];
                const float* srd = scb + r * SCW + 4 * cc;
                float4 v = { srd[0], srd[1], srd[2], srd[3] };
                if (n >= 0)
                    *(float4*)((char*)outp + (size_t)n * 256 + (size_t)lp * 128 + cc * 16) = v;
            }
            asm volatile("s_waitcnt lgkmcnt(0)" ::: "memory");
            __builtin_amdgcn_sched_barrier(0);
        }
    } else {
        // ---------- bf16 path (unchanged semantics) ----------
        for (int l = 0; l < L; l++) {
            s16x8 fr[NFRAG];
#pragma unroll
            for (int f = 0; f < NFRAG; f++)
                fr[f] = __builtin_bit_cast(s16x8, lw[(l * NFRAG + f) * 64 + lane]);

#pragma unroll
            for (int t = 0; t < 2; t++) {
                int n = n_t[t];
                int nn = n < 0 ? 0 : n;

                const char* xb = (const char*)rf;
                s16x8 B1 = __builtin_bit_cast(s16x8,
                     *(const uint4*)(xb + (size_t)nn * 128 + l * 32 + h * 16));

                f32x16 z = {0.0f};
                f32x16 d1 = __builtin_amdgcn_mfma_f32_32x32x16_bf16(fr[0], B1, z, 0, 0, 0);

                s16x8 Ba, Bb;
                d_to_b(d1, h, Ba, Bb);
                f32x16 d2 = __builtin_amdgcn_mfma_f32_32x32x16_bf16(fr[1], Ba, z, 0, 0, 0);
                d2 = __builtin_amdgcn_mfma_f32_32x32x16_bf16(fr[2], Bb, d2, 0, 0, 0);

                d_to_b(d2, h, Ba, Bb);
                f32x16 d3 = __builtin_amdgcn_mfma_f32_32x32x16_bf16(fr[3], Ba, z, 0, 0, 0);
                d3 = __builtin_amdgcn_mfma_f32_32x32x16_bf16(fr[4], Bb, d3, 0, 0, 0);

                d_to_b(d3, h, Ba, Bb);
                f32x16 d4 = __builtin_amdgcn_mfma_f32_32x32x16_bf16(fr[5], Ba, z, 0, 0, 0);
                d4 = __builtin_amdgcn_mfma_f32_32x32x16_bf16(fr[6], Bb, d4, 0, 0, 0);

                u32 P[4];
#pragma unroll
                for (int i = 0; i < 4; i++) P[i] = pack_bf16_hu(d4[2 * i], d4[2 * i + 1]);
                u32 E[4];
#pragma unroll
                for (int i = 0; i < 4; i++) E[i] = (u32)__shfl_xor((int)P[i], 32, 64);
                if (n >= 0) {
                    uint4 v = h ? make_uint4(E[2], E[3], P[2], P[3])
                                : make_uint4(P[0], P[1], E[0], E[1]);
                    char* ob = (char*)outp;
                    *(uint4*)(ob + (size_t)n * 128 + l * 32 + h * 16) = v;
                }
            }
        }
    }
}

extern "C" void kernel_launch(void* const* d_in, const int* in_sizes, int n_in,
                              void* d_out, int out_size, void* d_ws, size_t ws_size,
                              hipStream_t stream) {
    const void* rf     = d_in[0];
    const int* species = (const int*)d_in[1];
    const void* W1     = d_in[2];
    const void* W2     = d_in[3];
    const void* W3     = d_in[4];
    const void* W4     = d_in[5];

    int N = in_sizes[1];
    int* hdr   = (int*)d_ws;
    uint4* wf  = (uint4*)((char*)d_ws + 256);
    int* perm  = (int*)d_ws + WS_PERM_INT;

    int nb    = (N + BLK - 1) / BLK;
    int nwp   = (WF_ENTRIES + BLK - 1) / BLK;
    int grid4 = (N + S * (BLK - 1) + BLK - 1) / BLK;

    k_detect <<<dim3(1),    dim3(64),  0, stream>>>((const u32*)rf, (const u32*)species, hdr);
    k_wprep  <<<dim3(nwp),  dim3(BLK), 0, stream>>>(W1, W2, W3, W4, hdr, wf);
    k1_hist  <<<dim3(nb),   dim3(BLK), 0, stream>>>(species, hdr, N);
    k2_scan  <<<dim3(1),    dim3(BLK), 0, stream>>>(hdr, perm);
    k3_scatter<<<dim3(nb),  dim3(BLK), 0, stream>>>(species, hdr, perm, N);
    k4_mlp   <<<dim3(grid4),dim3(BLK), 0, stream>>>(rf, hdr, perm, wf, d_out);
}